// Round 11
// baseline (782.634 us; speedup 1.0000x reference)
//
#include <hip/hip_runtime.h>
#include <hip/hip_bf16.h>

// Problem constants
#define TT 2048
#define DD 512
#define HH 8
#define DH 64
#define LL 4
#define DFF 2048
#define NACT 18
#define TD3 1536   // 3*D

// d_out layout (flat, float32): logits [T,18], val [T], time [1], states [L,H,DH,DH]
#define OUT_LOGITS 0
#define OUT_VAL    (TT*NACT)            // 36864
#define OUT_TIME   (OUT_VAL + TT)       // 38912
#define OUT_STATES (OUT_TIME + 1)       // 38913

typedef __attribute__((ext_vector_type(8))) short bf16x8;
typedef __attribute__((ext_vector_type(4))) float f32x4;

__device__ inline unsigned short f2bf(float x) {
    __hip_bfloat16 h = __float2bfloat16(x);
    return *reinterpret_cast<unsigned short*>(&h);
}
__device__ inline float bf2f(unsigned short u) {
    __hip_bfloat16 h = *reinterpret_cast<__hip_bfloat16*>(&u);
    return __bfloat162float(h);
}

// async global->LDS, 16B per lane; lds dest must be wave-uniform base (+lane*16 implicit)
__device__ __forceinline__ void gload_lds16(const unsigned short* g, unsigned short* l) {
    __builtin_amdgcn_global_load_lds(
        (const __attribute__((address_space(1))) void*)g,
        (__attribute__((address_space(3))) void*)l, 16, 0, 0);
}

// ---------------------------------------------------------------------------
// Scan kernel: cumsum(done) -> c, reset-aware time, and the time output scalar.
// ---------------------------------------------------------------------------
__global__ __launch_bounds__(256) void k_scan(const unsigned char* __restrict__ done_raw,
                                              const int* __restrict__ state_obs,
                                              int* __restrict__ c_out,
                                              int* __restrict__ t_out,
                                              float* __restrict__ out_time)
{
    __shared__ int sc[TT];
    __shared__ int sm[TT];
    __shared__ int flags[3];
    const int tid = threadIdx.x;
    if (tid < 3) flags[tid] = 0;
    __syncthreads();

    int l0 = 0, l1 = 0, l23 = 0;
    for (int p = tid * 8; p < tid * 8 + 8; ++p) {
        unsigned char b = done_raw[p];
        if (b) {
            int m = p & 3;
            if (m == 0) l0 = 1; else if (m == 1) l1 = 1; else l23 = 1;
        }
    }
    if (l0)  atomicOr(&flags[0], 1);
    if (l1)  atomicOr(&flags[1], 1);
    if (l23) atomicOr(&flags[2], 1);
    __syncthreads();

    int mode; // 0 = int32, 1 = float32, 2 = uint8/bool
    if (flags[1] == 0 && flags[2] == 0)      mode = 0;
    else if (flags[0] == 0 && flags[1] == 0) mode = 1;
    else                                     mode = 2;

    const int so = state_obs[0];
    for (int i = tid; i < TT; i += 256) {
        int dn;
        if (mode == 0)      dn = (((const int*)done_raw)[i] != 0);
        else if (mode == 1) dn = (((const float*)done_raw)[i] != 0.0f);
        else                dn = (done_raw[i] != 0);
        sc[i] = dn;
        sm[i] = (so + i) * dn;
    }
    __syncthreads();

    const int NEG = (int)0x80000000;
    for (int off = 1; off < TT; off <<= 1) {
        int ts[8], tm[8];
        #pragma unroll
        for (int j = 0; j < 8; ++j) {
            int idx = tid + j * 256;
            if (idx >= off) { ts[j] = sc[idx - off]; tm[j] = sm[idx - off]; }
            else            { ts[j] = 0;            tm[j] = NEG; }
        }
        __syncthreads();
        #pragma unroll
        for (int j = 0; j < 8; ++j) {
            int idx = tid + j * 256;
            sc[idx] += ts[j];
            sm[idx] = max(sm[idx], tm[j]);
        }
        __syncthreads();
    }

    for (int i = tid; i < TT; i += 256) {
        c_out[i] = sc[i];
        t_out[i] = so + i - sm[i];
    }
    if (tid == 0) out_time[0] = (float)(so + (TT - 1) - sm[TT - 1] + 1);
}

// ---------------------------------------------------------------------------
// Fused input embedding + layer-0 ln1: one wave per row.
// ---------------------------------------------------------------------------
__global__ __launch_bounds__(64) void k_embed_ln(const float* __restrict__ obs,
                                                 const float* __restrict__ rew,
                                                 const int* __restrict__ act,
                                                 const int* __restrict__ tbuf,
                                                 const float* __restrict__ w_obs,
                                                 const float* __restrict__ b_obs,
                                                 const float* __restrict__ emb_act,
                                                 const float* __restrict__ w_rew,
                                                 const float* __restrict__ b_rew,
                                                 const float* __restrict__ emb_time,
                                                 const float* __restrict__ ln_s,
                                                 const float* __restrict__ ln_b,
                                                 float* __restrict__ x,
                                                 unsigned short* __restrict__ hbuf)
{
    const int t = blockIdx.x, lane = threadIdx.x;
    const float* orow = obs + t * 64;
    const float rp = rew[t];
    const float* ea = emb_act + act[t] * DD;
    const float* et = emb_time + tbuf[t] * DD;
    float v[8];
    float sum = 0.f;
    #pragma unroll
    for (int j = 0; j < 8; ++j) {
        const int d = lane + j * 64;
        float a = b_obs[d] + b_rew[d] + ea[d] + rp * w_rew[d] + et[d];
        for (int k = 0; k < 64; ++k) a += orow[k] * w_obs[k * DD + d];
        x[t * DD + d] = a;
        v[j] = a; sum += a;
    }
    #pragma unroll
    for (int off = 32; off >= 1; off >>= 1) sum += __shfl_xor(sum, off);
    const float mu = sum * (1.0f / DD);
    float vs = 0.f;
    #pragma unroll
    for (int j = 0; j < 8; ++j) { float d = v[j] - mu; vs += d * d; }
    #pragma unroll
    for (int off = 32; off >= 1; off >>= 1) vs += __shfl_xor(vs, off);
    const float rs = rsqrtf(vs * (1.0f / DD) + 1e-6f);
    #pragma unroll
    for (int j = 0; j < 8; ++j) {
        int d = lane + j * 64;
        hbuf[t * DD + d] = f2bf((v[j] - mu) * rs * ln_s[d] + ln_b[d]);
    }
}

// ---------------------------------------------------------------------------
// Fused split-K reduce + residual + LayerNorm (+ optional actor/critic heads).
// One wave per row (4 rows/block).
// ---------------------------------------------------------------------------
template<int NS, bool HEADS>
__global__ __launch_bounds__(256) void k_red_ln(float* __restrict__ x,
                                                const float* __restrict__ part,
                                                const float* __restrict__ bias,
                                                const float* __restrict__ ln_s,
                                                const float* __restrict__ ln_b,
                                                unsigned short* __restrict__ hbuf,
                                                const float* __restrict__ w_actor,
                                                const float* __restrict__ b_actor,
                                                const float* __restrict__ w_critic,
                                                const float* __restrict__ b_critic,
                                                float* __restrict__ out)
{
    __shared__ float xfs[4][DD];
    const int w4 = threadIdx.x >> 6;
    const int t = blockIdx.x * 4 + w4;
    const int lane = threadIdx.x & 63;
    float v[8];
    float sum = 0.f;
    #pragma unroll
    for (int j = 0; j < 8; ++j) {
        const int d = lane + j * 64;
        float a = x[(size_t)t * DD + d] + bias[d];
        #pragma unroll
        for (int z = 0; z < NS; ++z)
            a += part[(size_t)z * TT * DD + (size_t)t * DD + d];
        if (!HEADS) x[(size_t)t * DD + d] = a;
        v[j] = a; sum += a;
    }
    #pragma unroll
    for (int off = 32; off >= 1; off >>= 1) sum += __shfl_xor(sum, off);
    const float mu = sum * (1.0f / DD);
    float vs = 0.f;
    #pragma unroll
    for (int j = 0; j < 8; ++j) { float d = v[j] - mu; vs += d * d; }
    #pragma unroll
    for (int off = 32; off >= 1; off >>= 1) vs += __shfl_xor(vs, off);
    const float rs = rsqrtf(vs * (1.0f / DD) + 1e-6f);
    #pragma unroll
    for (int j = 0; j < 8; ++j) {
        int d = lane + j * 64;
        float xf = (v[j] - mu) * rs * ln_s[d] + ln_b[d];
        if (HEADS) xfs[w4][d] = xf;
        else       hbuf[(size_t)t * DD + d] = f2bf(xf);
    }
    if (HEADS) {
        // wave-local LDS (written+read by the same wave) -> no barrier needed
        if (lane < NACT) {
            float a = b_actor[lane];
            for (int k = 0; k < DD; ++k) a += xfs[w4][k] * w_actor[k * NACT + lane];
            out[OUT_LOGITS + t * NACT + lane] = a;
        } else if (lane == NACT) {
            float a = b_critic[0];
            for (int k = 0; k < DD; ++k) a += xfs[w4][k] * w_critic[k];
            out[OUT_VAL + t] = a;
        }
    }
}

// ---------------------------------------------------------------------------
// Weight convert+transpose for ALL layers in one launch:
// fp32 [K,N] -> bf16 [N,K], 4 matrices x 4 layers. grid (3072, L).
// ---------------------------------------------------------------------------
__global__ __launch_bounds__(256) void k_w2bf_all(const float* __restrict__ w_qkv,
                                                  const float* __restrict__ w_out,
                                                  const float* __restrict__ w_m1,
                                                  const float* __restrict__ w_m2,
                                                  unsigned short* __restrict__ wq_t,
                                                  unsigned short* __restrict__ wo_t,
                                                  unsigned short* __restrict__ wm1_t,
                                                  unsigned short* __restrict__ wm2_t)
{
    __shared__ float tile[32][33];
    const int t = blockIdx.x;
    const int i = blockIdx.y;  // layer
    const float* src; unsigned short* dst; int K, N, n0, k0;
    if (t < 768)       { src = w_qkv + (size_t)i * DD * TD3; dst = wq_t  + (size_t)i * TD3 * DD; K = 512;  N = 1536; int l = t;        n0 = (l % 48) * 32; k0 = (l / 48) * 32; }
    else if (t < 1024) { src = w_out + (size_t)i * DD * DD;  dst = wo_t  + (size_t)i * DD * DD;  K = 512;  N = 512;  int l = t - 768;  n0 = (l % 16) * 32; k0 = (l / 16) * 32; }
    else if (t < 2048) { src = w_m1 + (size_t)i * DD * DFF;  dst = wm1_t + (size_t)i * DFF * DD; K = 512;  N = 2048; int l = t - 1024; n0 = (l % 64) * 32; k0 = (l / 64) * 32; }
    else               { src = w_m2 + (size_t)i * DFF * DD;  dst = wm2_t + (size_t)i * DD * DFF; K = 2048; N = 512;  int l = t - 2048; n0 = (l % 16) * 32; k0 = (l / 16) * 32; }
    const int tx = threadIdx.x & 31, ty = threadIdx.x >> 5;  // 32 x 8
    #pragma unroll
    for (int j = 0; j < 4; ++j)
        tile[ty + 8 * j][tx] = src[(size_t)(k0 + ty + 8 * j) * N + n0 + tx];
    __syncthreads();
    #pragma unroll
    for (int j = 0; j < 4; ++j)
        dst[(size_t)(n0 + ty + 8 * j) * K + k0 + tx] = f2bf(tile[tx][ty + 8 * j]);
}

// ---------------------------------------------------------------------------
// bf16 MFMA GEMM v5: 128x64 tile, BK=32, global_load_lds staging (linear LDS),
// XCD-chunked swizzle. KSPLIT==1: bf16 out (+bias,+GELU); KSPLIT>1: fp32
// partials at Yf + z*M*N (no bias), plain stores.
// ---------------------------------------------------------------------------
__device__ inline float gelu_tanh(float x) {
    float x3 = x * x * x;
    return 0.5f * x * (1.0f + tanhf(0.7978845608028654f * (x + 0.044715f * x3)));
}

template<int KSPLIT, bool GELU_>
__global__ __launch_bounds__(256) void k_gemm5(const unsigned short* __restrict__ A,
                                               const unsigned short* __restrict__ Bt,
                                               const float* __restrict__ bias,
                                               float* __restrict__ Yf,
                                               unsigned short* __restrict__ Yb,
                                               int M, int N, int K)
{
    __shared__ __align__(16) unsigned short As[128][32];   // linear: 64B rows (gload_lds dest)
    __shared__ __align__(16) unsigned short Bs[64][32];

    // XCD-chunked swizzle over (x,y); z independent. nwg % 8 == 0 for all grids.
    const int gx = gridDim.x;
    const int nwg = gx * gridDim.y;
    const int bid = blockIdx.y * gx + blockIdx.x;
    const int logical = (bid % 8) * (nwg / 8) + bid / 8;
    const int bm = (logical / gx) * 128, bn = (logical % gx) * 64;

    const int kslice = K / KSPLIT;
    const int kbase = (KSPLIT > 1) ? blockIdx.z * kslice : 0;

    const int tid = threadIdx.x;
    const int lane = tid & 63;
    const int wid = tid >> 6;
    const int l16 = lane & 15, l4 = lane >> 4;
    const int lr = lane >> 2;          // 0..15 (row within 16-row chunk)
    const int lc = (lane & 3) * 8;     // elem offset within 32-elem row

    // per-wave staging chunks: A rows [wid*16,+16) and [64+wid*16,+16); B rows [wid*16,+16)
    const unsigned short* gA0 = A  + (size_t)(bm + wid * 16 + lr) * K + kbase + lc;
    const unsigned short* gA1 = A  + (size_t)(bm + 64 + wid * 16 + lr) * K + kbase + lc;
    const unsigned short* gB  = Bt + (size_t)(bn + wid * 16 + lr) * K + kbase + lc;
    unsigned short* lA0 = &As[wid * 16][0];
    unsigned short* lA1 = &As[64 + wid * 16][0];
    unsigned short* lB  = &Bs[wid * 16][0];

    f32x4 acc[2][4];
    #pragma unroll
    for (int m = 0; m < 2; ++m)
        #pragma unroll
        for (int n = 0; n < 4; ++n)
            acc[m][n] = (f32x4){0.f, 0.f, 0.f, 0.f};

    for (int k0 = 0; k0 < kslice; k0 += 32) {
        gload_lds16(gA0 + k0, lA0);
        gload_lds16(gA1 + k0, lA1);
        gload_lds16(gB + k0, lB);
        __syncthreads();   // drains vmcnt (gload_lds) before LDS reads
        bf16x8 a[2], b[4];
        a[0] = *(bf16x8*)&As[wid * 32 + l16][l4 * 8];
        a[1] = *(bf16x8*)&As[wid * 32 + 16 + l16][l4 * 8];
        #pragma unroll
        for (int n = 0; n < 4; ++n) b[n] = *(bf16x8*)&Bs[n * 16 + l16][l4 * 8];
        #pragma unroll
        for (int m = 0; m < 2; ++m)
            #pragma unroll
            for (int n = 0; n < 4; ++n)
                acc[m][n] = __builtin_amdgcn_mfma_f32_16x16x32_bf16(a[m], b[n], acc[m][n], 0, 0, 0);
        __syncthreads();   // all reads done before next-iter staging overwrites
    }

    if (KSPLIT > 1) {
        float* P = Yf + (size_t)blockIdx.z * M * N;
        #pragma unroll
        for (int m = 0; m < 2; ++m)
            #pragma unroll
            for (int n = 0; n < 4; ++n) {
                const int col = bn + n * 16 + l16;
                #pragma unroll
                for (int r = 0; r < 4; ++r) {
                    const int row = bm + wid * 32 + m * 16 + l4 * 4 + r;
                    P[(size_t)row * N + col] = acc[m][n][r];
                }
            }
    } else {
        #pragma unroll
        for (int m = 0; m < 2; ++m)
            #pragma unroll
            for (int n = 0; n < 4; ++n) {
                const int col = bn + n * 16 + l16;
                const float bz = bias[col];
                #pragma unroll
                for (int r = 0; r < 4; ++r) {
                    const int row = bm + wid * 32 + m * 16 + l4 * 4 + r;
                    float v = acc[m][n][r] + bz;
                    if (GELU_) v = gelu_tanh(v);
                    Yb[(size_t)row * N + col] = f2bf(v);
                }
            }
    }
}

// ---------------------------------------------------------------------------
// MFMA masked linear attention. One block per (64-row q-tile, head), 4 waves.
// ---------------------------------------------------------------------------
__global__ __launch_bounds__(256) void k_attn_mfma(const unsigned short* __restrict__ qkv,
                                                   const int* __restrict__ c,
                                                   const float* __restrict__ SB,  // [H,DH,DH]
                                                   unsigned short* __restrict__ out)
{
    __shared__ __align__(16) unsigned short Qs[64][72];
    __shared__ __align__(16) unsigned short Ks[64][72];
    __shared__ __align__(16) unsigned short VsT[64][72];  // VsT[e][s]
    __shared__ __align__(16) unsigned short Ss[64][72];   // S[q][s]; reused as SBsT[e][k] pre-loop
    __shared__ int cq[64], cs[64];
    const int h = blockIdx.y;
    const int q0 = blockIdx.x * 64;
    const int tid = threadIdx.x;
    const int lane = tid & 63;
    const int wid = tid >> 6;
    const int l16 = lane & 15, l4 = lane >> 4;
    const int wrow = wid * 16;
    const int r1 = tid >> 3, ccol = (tid & 7) * 8;

    *(bf16x8*)&Qs[r1][ccol]      = *(const bf16x8*)(qkv + (size_t)(q0 + r1) * TD3 + h * 64 + ccol);
    *(bf16x8*)&Qs[r1 + 32][ccol] = *(const bf16x8*)(qkv + (size_t)(q0 + r1 + 32) * TD3 + h * 64 + ccol);
    if (tid < 64) cq[tid] = c[q0 + tid];
    __syncthreads();
    const int cq0 = cq[0];

    f32x4 o[4];
    #pragma unroll
    for (int n = 0; n < 4; ++n) o[n] = (f32x4){0.f, 0.f, 0.f, 0.f};

    if (cq0 == 0) {
        for (int i = tid; i < 4096; i += 256) {
            int k = i >> 6, e = i & 63;
            Ss[e][k] = f2bf(SB[(h * 64 + k) * 64 + e]);
        }
        __syncthreads();
        bf16x8 aq0 = *(bf16x8*)&Qs[wrow + l16][l4 * 8];
        bf16x8 aq1 = *(bf16x8*)&Qs[wrow + l16][32 + l4 * 8];
        if (cq[wrow + l16] != 0) {
            aq0 = (bf16x8){0, 0, 0, 0, 0, 0, 0, 0};
            aq1 = (bf16x8){0, 0, 0, 0, 0, 0, 0, 0};
        }
        #pragma unroll
        for (int n = 0; n < 4; ++n) {
            o[n] = __builtin_amdgcn_mfma_f32_16x16x32_bf16(aq0, *(bf16x8*)&Ss[n * 16 + l16][l4 * 8], o[n], 0, 0, 0);
            o[n] = __builtin_amdgcn_mfma_f32_16x16x32_bf16(aq1, *(bf16x8*)&Ss[n * 16 + l16][32 + l4 * 8], o[n], 0, 0, 0);
        }
        __syncthreads();
    }

    for (int st = blockIdx.x; st >= 0; --st) {
        const int s0 = st * 64;
        if (st < (int)blockIdx.x && c[s0 + 63] < cq0) break;

        *(bf16x8*)&Ks[r1][ccol]      = *(const bf16x8*)(qkv + (size_t)(s0 + r1) * TD3 + 512 + h * 64 + ccol);
        *(bf16x8*)&Ks[r1 + 32][ccol] = *(const bf16x8*)(qkv + (size_t)(s0 + r1 + 32) * TD3 + 512 + h * 64 + ccol);
        {
            bf16x8 v1 = *(const bf16x8*)(qkv + (size_t)(s0 + r1) * TD3 + 1024 + h * 64 + ccol);
            bf16x8 v2 = *(const bf16x8*)(qkv + (size_t)(s0 + r1 + 32) * TD3 + 1024 + h * 64 + ccol);
            #pragma unroll
            for (int j = 0; j < 8; ++j) {
                VsT[ccol + j][r1]      = (unsigned short)v1[j];
                VsT[ccol + j][r1 + 32] = (unsigned short)v2[j];
            }
        }
        if (tid < 64) cs[tid] = c[s0 + tid];
        __syncthreads();

        f32x4 s_acc[4];
        #pragma unroll
        for (int n = 0; n < 4; ++n) s_acc[n] = (f32x4){0.f, 0.f, 0.f, 0.f};
        bf16x8 aq0 = *(bf16x8*)&Qs[wrow + l16][l4 * 8];
        bf16x8 aq1 = *(bf16x8*)&Qs[wrow + l16][32 + l4 * 8];
        #pragma unroll
        for (int n = 0; n < 4; ++n) {
            s_acc[n] = __builtin_amdgcn_mfma_f32_16x16x32_bf16(aq0, *(bf16x8*)&Ks[n * 16 + l16][l4 * 8], s_acc[n], 0, 0, 0);
            s_acc[n] = __builtin_amdgcn_mfma_f32_16x16x32_bf16(aq1, *(bf16x8*)&Ks[n * 16 + l16][32 + l4 * 8], s_acc[n], 0, 0, 0);
        }
        #pragma unroll
        for (int n = 0; n < 4; ++n) {
            const int sc_ = n * 16 + l16;
            const int sg = s0 + sc_;
            const int csv = cs[sc_];
            #pragma unroll
            for (int r = 0; r < 4; ++r) {
                const int qrow = wrow + l4 * 4 + r;
                float v = s_acc[n][r];
                if (!((q0 + qrow) >= sg && cq[qrow] == csv)) v = 0.f;
                Ss[qrow][sc_] = f2bf(v);
            }
        }
        bf16x8 as0 = *(bf16x8*)&Ss[wrow + l16][l4 * 8];
        bf16x8 as1 = *(bf16x8*)&Ss[wrow + l16][32 + l4 * 8];
        #pragma unroll
        for (int n = 0; n < 4; ++n) {
            o[n] = __builtin_amdgcn_mfma_f32_16x16x32_bf16(as0, *(bf16x8*)&VsT[n * 16 + l16][l4 * 8], o[n], 0, 0, 0);
            o[n] = __builtin_amdgcn_mfma_f32_16x16x32_bf16(as1, *(bf16x8*)&VsT[n * 16 + l16][32 + l4 * 8], o[n], 0, 0, 0);
        }
        __syncthreads();
    }

    #pragma unroll
    for (int n = 0; n < 4; ++n) {
        const int e = n * 16 + l16;
        #pragma unroll
        for (int r = 0; r < 4; ++r) {
            const int qrow = wrow + l4 * 4 + r;
            out[(size_t)(q0 + qrow) * DD + h * 64 + e] = f2bf(o[n][r]);
        }
    }
}

// ---------------------------------------------------------------------------
// State init: out = done_any ? 0 : state_blocks
// ---------------------------------------------------------------------------
__global__ __launch_bounds__(256) void k_state_init(const float* __restrict__ SB_all,
                                                    const int* __restrict__ c,
                                                    float* __restrict__ out)
{
    const int idx = blockIdx.x * 256 + threadIdx.x;
    const bool any = c[TT - 1] > 0;
    out[idx] = any ? 0.0f : SB_all[idx];
}

// ---------------------------------------------------------------------------
// State accumulate (bf16 qkv): out[h,d,e] += sum_{t: c[t]==c_last} k[t,d]*v[t,e]
// grid (32, H): 64 timesteps per block.
// ---------------------------------------------------------------------------
__global__ __launch_bounds__(256) void k_state_acc(const unsigned short* __restrict__ qkv,
                                                   const int* __restrict__ c,
                                                   float* __restrict__ st_out)
{
    const int h = blockIdx.y;
    const int t0 = blockIdx.x * 64;
    const int tid = threadIdx.x;
    const int d = tid >> 2;
    const int e0 = (tid & 3) * 16;
    const int cl = c[TT - 1];
    float acc[16] = {};
    for (int t = t0; t < t0 + 64; ++t) {
        if (c[t] == cl) {
            float kd = bf2f(qkv[(size_t)t * TD3 + 512 + h * 64 + d]);
            const bf16x8* vr = (const bf16x8*)(qkv + (size_t)t * TD3 + 1024 + h * 64 + e0);
            bf16x8 va = vr[0], vb = vr[1];
            #pragma unroll
            for (int e = 0; e < 8; ++e) acc[e]     += kd * bf2f((unsigned short)va[e]);
            #pragma unroll
            for (int e = 0; e < 8; ++e) acc[e + 8] += kd * bf2f((unsigned short)vb[e]);
        }
    }
    #pragma unroll
    for (int e = 0; e < 16; ++e)
        atomicAdd(&st_out[(h * 64 + d) * 64 + e0 + e], acc[e]);
}

// ---------------------------------------------------------------------------
extern "C" void kernel_launch(void* const* d_in, const int* in_sizes, int n_in,
                              void* d_out, int out_size, void* d_ws, size_t ws_size,
                              hipStream_t stream)
{
    const float* obs        = (const float*)d_in[0];
    const float* rew_p      = (const float*)d_in[1];
    const int*   act_p      = (const int*)d_in[2];
    const unsigned char* done = (const unsigned char*)d_in[3];
    const int*   state_obs  = (const int*)d_in[4];
    const float* state_blocks = (const float*)d_in[5];
    const float* w_obs      = (const float*)d_in[6];
    const float* b_obs      = (const float*)d_in[7];
    const float* emb_act    = (const float*)d_in[8];
    const float* w_rew      = (const float*)d_in[9];
    const float* b_rew      = (const float*)d_in[10];
    const float* emb_time   = (const float*)d_in[11];
    const float* ln1_s      = (const float*)d_in[12];
    const float* ln1_b      = (const float*)d_in[13];
    const float* w_qkv      = (const float*)d_in[14];
    const float* b_qkv      = (const float*)d_in[15];
    const float* w_out      = (const float*)d_in[16];
    const float* b_out      = (const float*)d_in[17];
    const float* ln2_s      = (const float*)d_in[18];
    const float* ln2_b      = (const float*)d_in[19];
    const float* w_m1       = (const float*)d_in[20];
    const float* b_m1       = (const float*)d_in[21];
    const float* w_m2       = (const float*)d_in[22];
    const float* b_m2       = (const float*)d_in[23];
    const float* lnf_s      = (const float*)d_in[24];
    const float* lnf_b      = (const float*)d_in[25];
    const float* w_actor    = (const float*)d_in[26];
    const float* b_actor    = (const float*)d_in[27];
    const float* w_critic   = (const float*)d_in[28];
    const float* b_critic   = (const float*)d_in[29];

    float* out = (float*)d_out;

    // workspace layout
    char* ws = (char*)d_ws;
    int*   c_buf = (int*)ws;                             // [T]
    int*   t_buf = c_buf + TT;                           // [T]
    float* x     = (float*)(ws + 16384);                 // [T,D] fp32 (4MB)
    float* part  = x + (size_t)TT * DD;                  // [4,T,D] fp32 (16MB)
    unsigned short* qkvb = (unsigned short*)(part + (size_t)4 * TT * DD);  // [T,3D] bf16 (6MB)
    unsigned short* hbuf = qkvb + (size_t)TT * TD3;      // [T,D] bf16 (2MB)
    unsigned short* aout = hbuf + (size_t)TT * DD;       // [T,D] bf16 (2MB)
    unsigned short* mid  = aout + (size_t)TT * DD;       // [T,DFF] bf16 (8MB)
    unsigned short* wq_t = mid + (size_t)TT * DFF;       // [L,3D,D] bf16 (6MB)
    unsigned short* wo_t = wq_t + (size_t)LL * TD3 * DD; // [L,D,D] (2MB)
    unsigned short* wm1_t = wo_t + (size_t)LL * DD * DD; // [L,DFF,D] (8MB)
    unsigned short* wm2_t = wm1_t + (size_t)LL * DFF * DD; // [L,D,DFF] (8MB)

    // 1) scans (c, time) + time output
    k_scan<<<1, 256, 0, stream>>>(done, state_obs, c_buf, t_buf, out + OUT_TIME);

    // 2) fused embedding + layer-0 ln1
    k_embed_ln<<<TT, 64, 0, stream>>>(obs, rew_p, act_p, t_buf, w_obs, b_obs,
                                      emb_act, w_rew, b_rew, emb_time,
                                      ln1_s, ln1_b, x, hbuf);

    // 3) init states output
    k_state_init<<<LL * HH * DH * DH / 256, 256, 0, stream>>>(state_blocks, c_buf, out + OUT_STATES);

    // 4) all weight transposes in one launch
    k_w2bf_all<<<dim3(3072, LL), 256, 0, stream>>>(
        w_qkv, w_out, w_m1, w_m2, wq_t, wo_t, wm1_t, wm2_t);

    // 5) transformer layers (all GEMMs: 128x64 tiles, gload_lds staging)
    for (int i = 0; i < LL; ++i) {
        // qkv: [T,512]@[512,1536] -> bf16. grid 24x16 = 384 blocks.
        k_gemm5<1, false><<<dim3(TD3 / 64, TT / 128), 256, 0, stream>>>(
            hbuf, wq_t + (size_t)i * TD3 * DD, b_qkv + i * TD3, nullptr, qkvb, TT, TD3, DD);
        k_attn_mfma<<<dim3(TT / 64, HH), 256, 0, stream>>>(
            qkvb, c_buf, state_blocks + (size_t)i * HH * DH * DH, aout);
        k_state_acc<<<dim3(32, HH), 256, 0, stream>>>(
            qkvb, c_buf, out + OUT_STATES + (size_t)i * HH * DH * DH);
        // out-proj: [T,512]@[512,512], split-K=2 -> partials. grid 8x16x2 = 256.
        k_gemm5<2, false><<<dim3(DD / 64, TT / 128, 2), 256, 0, stream>>>(
            aout, wo_t + (size_t)i * DD * DD, nullptr, part, nullptr, TT, DD, DD);
        // fused reduce(2) + residual + ln2 -> x, hbuf
        k_red_ln<2, false><<<TT / 4, 256, 0, stream>>>(x, part, b_out + i * DD,
            ln2_s + i * DD, ln2_b + i * DD, hbuf, nullptr, nullptr, nullptr, nullptr, nullptr);
        // m1: [T,512]@[512,2048] + gelu -> bf16 mid. grid 32x16 = 512 blocks.
        k_gemm5<1, true><<<dim3(DFF / 64, TT / 128), 256, 0, stream>>>(
            hbuf, wm1_t + (size_t)i * DFF * DD, b_m1 + i * DFF, nullptr, mid, TT, DFF, DD);
        // m2: [T,2048]@[2048,512], split-K=4 -> partials. grid 8x16x4 = 512.
        k_gemm5<4, false><<<dim3(DD / 64, TT / 128, 4), 256, 0, stream>>>(
            mid, wm2_t + (size_t)i * DD * DFF, nullptr, part, nullptr, TT, DD, DFF);
        // fused reduce(4) + residual + next-LN; last layer also computes heads
        if (i < LL - 1) {
            k_red_ln<4, false><<<TT / 4, 256, 0, stream>>>(x, part, b_m2 + i * DD,
                ln1_s + (i + 1) * DD, ln1_b + (i + 1) * DD, hbuf,
                nullptr, nullptr, nullptr, nullptr, nullptr);
        } else {
            k_red_ln<4, true><<<TT / 4, 256, 0, stream>>>(x, part, b_m2 + i * DD,
                lnf_s, lnf_b, hbuf, w_actor, b_actor, w_critic, b_critic, out);
        }
    }
}

// Round 13
// 579.844 us; speedup vs baseline: 1.3497x; 1.3497x over previous
//
#include <hip/hip_runtime.h>
#include <hip/hip_bf16.h>

// Problem constants
#define TT 2048
#define DD 512
#define HH 8
#define DH 64
#define LL 4
#define DFF 2048
#define NACT 18
#define TD3 1536   // 3*D

// d_out layout (flat, float32): logits [T,18], val [T], time [1], states [L,H,DH,DH]
#define OUT_LOGITS 0
#define OUT_VAL    (TT*NACT)            // 36864
#define OUT_TIME   (OUT_VAL + TT)       // 38912
#define OUT_STATES (OUT_TIME + 1)       // 38913

typedef __attribute__((ext_vector_type(8))) short bf16x8;
typedef __attribute__((ext_vector_type(4))) float f32x4;

__device__ inline unsigned short f2bf(float x) {
    __hip_bfloat16 h = __float2bfloat16(x);
    return *reinterpret_cast<unsigned short*>(&h);
}
__device__ inline float bf2f(unsigned short u) {
    __hip_bfloat16 h = *reinterpret_cast<__hip_bfloat16*>(&u);
    return __bfloat162float(h);
}

// async global->LDS, 16B per lane; lds dest must be wave-uniform base (+lane*16 implicit)
__device__ __forceinline__ void gload_lds16(const unsigned short* g, unsigned short* l) {
    __builtin_amdgcn_global_load_lds(
        (const __attribute__((address_space(1))) void*)g,
        (__attribute__((address_space(3))) void*)l, 16, 0, 0);
}

// ---------------------------------------------------------------------------
// Scan kernel: cumsum(done) -> c, reset-aware time, and the time output scalar.
// ---------------------------------------------------------------------------
__global__ __launch_bounds__(256) void k_scan(const unsigned char* __restrict__ done_raw,
                                              const int* __restrict__ state_obs,
                                              int* __restrict__ c_out,
                                              int* __restrict__ t_out,
                                              float* __restrict__ out_time)
{
    __shared__ int sc[TT];
    __shared__ int sm[TT];
    __shared__ int flags[3];
    const int tid = threadIdx.x;
    if (tid < 3) flags[tid] = 0;
    __syncthreads();

    int l0 = 0, l1 = 0, l23 = 0;
    for (int p = tid * 8; p < tid * 8 + 8; ++p) {
        unsigned char b = done_raw[p];
        if (b) {
            int m = p & 3;
            if (m == 0) l0 = 1; else if (m == 1) l1 = 1; else l23 = 1;
        }
    }
    if (l0)  atomicOr(&flags[0], 1);
    if (l1)  atomicOr(&flags[1], 1);
    if (l23) atomicOr(&flags[2], 1);
    __syncthreads();

    int mode; // 0 = int32, 1 = float32, 2 = uint8/bool
    if (flags[1] == 0 && flags[2] == 0)      mode = 0;
    else if (flags[0] == 0 && flags[1] == 0) mode = 1;
    else                                     mode = 2;

    const int so = state_obs[0];
    for (int i = tid; i < TT; i += 256) {
        int dn;
        if (mode == 0)      dn = (((const int*)done_raw)[i] != 0);
        else if (mode == 1) dn = (((const float*)done_raw)[i] != 0.0f);
        else                dn = (done_raw[i] != 0);
        sc[i] = dn;
        sm[i] = (so + i) * dn;
    }
    __syncthreads();

    const int NEG = (int)0x80000000;
    for (int off = 1; off < TT; off <<= 1) {
        int ts[8], tm[8];
        #pragma unroll
        for (int j = 0; j < 8; ++j) {
            int idx = tid + j * 256;
            if (idx >= off) { ts[j] = sc[idx - off]; tm[j] = sm[idx - off]; }
            else            { ts[j] = 0;            tm[j] = NEG; }
        }
        __syncthreads();
        #pragma unroll
        for (int j = 0; j < 8; ++j) {
            int idx = tid + j * 256;
            sc[idx] += ts[j];
            sm[idx] = max(sm[idx], tm[j]);
        }
        __syncthreads();
    }

    for (int i = tid; i < TT; i += 256) {
        c_out[i] = sc[i];
        t_out[i] = so + i - sm[i];
    }
    if (tid == 0) out_time[0] = (float)(so + (TT - 1) - sm[TT - 1] + 1);
}

// ---------------------------------------------------------------------------
// Fused input embedding + layer-0 ln1: one wave per row.
// ---------------------------------------------------------------------------
__global__ __launch_bounds__(64) void k_embed_ln(const float* __restrict__ obs,
                                                 const float* __restrict__ rew,
                                                 const int* __restrict__ act,
                                                 const int* __restrict__ tbuf,
                                                 const float* __restrict__ w_obs,
                                                 const float* __restrict__ b_obs,
                                                 const float* __restrict__ emb_act,
                                                 const float* __restrict__ w_rew,
                                                 const float* __restrict__ b_rew,
                                                 const float* __restrict__ emb_time,
                                                 const float* __restrict__ ln_s,
                                                 const float* __restrict__ ln_b,
                                                 float* __restrict__ x,
                                                 unsigned short* __restrict__ hbuf)
{
    const int t = blockIdx.x, lane = threadIdx.x;
    const float* orow = obs + t * 64;
    const float rp = rew[t];
    const float* ea = emb_act + act[t] * DD;
    const float* et = emb_time + tbuf[t] * DD;
    float v[8];
    float sum = 0.f;
    #pragma unroll
    for (int j = 0; j < 8; ++j) {
        const int d = lane + j * 64;
        float a = b_obs[d] + b_rew[d] + ea[d] + rp * w_rew[d] + et[d];
        for (int k = 0; k < 64; ++k) a += orow[k] * w_obs[k * DD + d];
        x[t * DD + d] = a;
        v[j] = a; sum += a;
    }
    #pragma unroll
    for (int off = 32; off >= 1; off >>= 1) sum += __shfl_xor(sum, off);
    const float mu = sum * (1.0f / DD);
    float vs = 0.f;
    #pragma unroll
    for (int j = 0; j < 8; ++j) { float d = v[j] - mu; vs += d * d; }
    #pragma unroll
    for (int off = 32; off >= 1; off >>= 1) vs += __shfl_xor(vs, off);
    const float rs = rsqrtf(vs * (1.0f / DD) + 1e-6f);
    #pragma unroll
    for (int j = 0; j < 8; ++j) {
        int d = lane + j * 64;
        hbuf[t * DD + d] = f2bf((v[j] - mu) * rs * ln_s[d] + ln_b[d]);
    }
}

// ---------------------------------------------------------------------------
// Fused split-K reduce + residual + LayerNorm (+ optional actor/critic heads).
// One wave per row (4 rows/block).
// ---------------------------------------------------------------------------
template<int NS, bool HEADS>
__global__ __launch_bounds__(256) void k_red_ln(float* __restrict__ x,
                                                const float* __restrict__ part,
                                                const float* __restrict__ bias,
                                                const float* __restrict__ ln_s,
                                                const float* __restrict__ ln_b,
                                                unsigned short* __restrict__ hbuf,
                                                const float* __restrict__ w_actor,
                                                const float* __restrict__ b_actor,
                                                const float* __restrict__ w_critic,
                                                const float* __restrict__ b_critic,
                                                float* __restrict__ out)
{
    __shared__ float xfs[4][DD];
    const int w4 = threadIdx.x >> 6;
    const int t = blockIdx.x * 4 + w4;
    const int lane = threadIdx.x & 63;
    float v[8];
    float sum = 0.f;
    #pragma unroll
    for (int j = 0; j < 8; ++j) {
        const int d = lane + j * 64;
        float a = x[(size_t)t * DD + d] + bias[d];
        #pragma unroll
        for (int z = 0; z < NS; ++z)
            a += part[(size_t)z * TT * DD + (size_t)t * DD + d];
        if (!HEADS) x[(size_t)t * DD + d] = a;
        v[j] = a; sum += a;
    }
    #pragma unroll
    for (int off = 32; off >= 1; off >>= 1) sum += __shfl_xor(sum, off);
    const float mu = sum * (1.0f / DD);
    float vs = 0.f;
    #pragma unroll
    for (int j = 0; j < 8; ++j) { float d = v[j] - mu; vs += d * d; }
    #pragma unroll
    for (int off = 32; off >= 1; off >>= 1) vs += __shfl_xor(vs, off);
    const float rs = rsqrtf(vs * (1.0f / DD) + 1e-6f);
    #pragma unroll
    for (int j = 0; j < 8; ++j) {
        int d = lane + j * 64;
        float xf = (v[j] - mu) * rs * ln_s[d] + ln_b[d];
        if (HEADS) xfs[w4][d] = xf;
        else       hbuf[(size_t)t * DD + d] = f2bf(xf);
    }
    if (HEADS) {
        // wave-local LDS (written+read by the same wave) -> no barrier needed
        if (lane < NACT) {
            float a = b_actor[lane];
            for (int k = 0; k < DD; ++k) a += xfs[w4][k] * w_actor[k * NACT + lane];
            out[OUT_LOGITS + t * NACT + lane] = a;
        } else if (lane == NACT) {
            float a = b_critic[0];
            for (int k = 0; k < DD; ++k) a += xfs[w4][k] * w_critic[k];
            out[OUT_VAL + t] = a;
        }
    }
}

// ---------------------------------------------------------------------------
// Weight convert+transpose for ALL layers in one launch:
// fp32 [K,N] -> bf16 [N,K], 4 matrices x 4 layers. grid (3072, L).
// ---------------------------------------------------------------------------
__global__ __launch_bounds__(256) void k_w2bf_all(const float* __restrict__ w_qkv,
                                                  const float* __restrict__ w_out,
                                                  const float* __restrict__ w_m1,
                                                  const float* __restrict__ w_m2,
                                                  unsigned short* __restrict__ wq_t,
                                                  unsigned short* __restrict__ wo_t,
                                                  unsigned short* __restrict__ wm1_t,
                                                  unsigned short* __restrict__ wm2_t)
{
    __shared__ float tile[32][33];
    const int t = blockIdx.x;
    const int i = blockIdx.y;  // layer
    const float* src; unsigned short* dst; int K, N, n0, k0;
    if (t < 768)       { src = w_qkv + (size_t)i * DD * TD3; dst = wq_t  + (size_t)i * TD3 * DD; K = 512;  N = 1536; int l = t;        n0 = (l % 48) * 32; k0 = (l / 48) * 32; }
    else if (t < 1024) { src = w_out + (size_t)i * DD * DD;  dst = wo_t  + (size_t)i * DD * DD;  K = 512;  N = 512;  int l = t - 768;  n0 = (l % 16) * 32; k0 = (l / 16) * 32; }
    else if (t < 2048) { src = w_m1 + (size_t)i * DD * DFF;  dst = wm1_t + (size_t)i * DFF * DD; K = 512;  N = 2048; int l = t - 1024; n0 = (l % 64) * 32; k0 = (l / 64) * 32; }
    else               { src = w_m2 + (size_t)i * DFF * DD;  dst = wm2_t + (size_t)i * DD * DFF; K = 2048; N = 512;  int l = t - 2048; n0 = (l % 16) * 32; k0 = (l / 16) * 32; }
    const int tx = threadIdx.x & 31, ty = threadIdx.x >> 5;  // 32 x 8
    #pragma unroll
    for (int j = 0; j < 4; ++j)
        tile[ty + 8 * j][tx] = src[(size_t)(k0 + ty + 8 * j) * N + n0 + tx];
    __syncthreads();
    #pragma unroll
    for (int j = 0; j < 4; ++j)
        dst[(size_t)(n0 + ty + 8 * j) * K + k0 + tx] = f2bf(tile[tx][ty + 8 * j]);
}

// ---------------------------------------------------------------------------
// bf16 MFMA GEMM v5: 128x64 tile, BK=32, global_load_lds staging (linear LDS),
// XCD-chunked swizzle. KSPLIT==1: bf16 out (+bias,+GELU); KSPLIT>1: fp32
// partials at Yf + z*M*N (no bias), plain stores.
// ---------------------------------------------------------------------------
__device__ inline float gelu_tanh(float x) {
    float x3 = x * x * x;
    return 0.5f * x * (1.0f + tanhf(0.7978845608028654f * (x + 0.044715f * x3)));
}

template<int KSPLIT, bool GELU_>
__global__ __launch_bounds__(256) void k_gemm5(const unsigned short* __restrict__ A,
                                               const unsigned short* __restrict__ Bt,
                                               const float* __restrict__ bias,
                                               float* __restrict__ Yf,
                                               unsigned short* __restrict__ Yb,
                                               int M, int N, int K)
{
    __shared__ __align__(16) unsigned short As[128][32];   // linear: 64B rows (gload_lds dest)
    __shared__ __align__(16) unsigned short Bs[64][32];

    // XCD-chunked swizzle over (x,y); z independent. nwg % 8 == 0 for all grids.
    const int gx = gridDim.x;
    const int nwg = gx * gridDim.y;
    const int bid = blockIdx.y * gx + blockIdx.x;
    const int logical = (bid % 8) * (nwg / 8) + bid / 8;
    const int bm = (logical / gx) * 128, bn = (logical % gx) * 64;

    const int kslice = K / KSPLIT;
    const int kbase = (KSPLIT > 1) ? blockIdx.z * kslice : 0;

    const int tid = threadIdx.x;
    const int lane = tid & 63;
    const int wid = tid >> 6;
    const int l16 = lane & 15, l4 = lane >> 4;
    const int lr = lane >> 2;          // 0..15 (row within 16-row chunk)
    const int lc = (lane & 3) * 8;     // elem offset within 32-elem row

    // per-wave staging chunks: A rows [wid*16,+16) and [64+wid*16,+16); B rows [wid*16,+16)
    const unsigned short* gA0 = A  + (size_t)(bm + wid * 16 + lr) * K + kbase + lc;
    const unsigned short* gA1 = A  + (size_t)(bm + 64 + wid * 16 + lr) * K + kbase + lc;
    const unsigned short* gB  = Bt + (size_t)(bn + wid * 16 + lr) * K + kbase + lc;
    unsigned short* lA0 = &As[wid * 16][0];
    unsigned short* lA1 = &As[64 + wid * 16][0];
    unsigned short* lB  = &Bs[wid * 16][0];

    f32x4 acc[2][4];
    #pragma unroll
    for (int m = 0; m < 2; ++m)
        #pragma unroll
        for (int n = 0; n < 4; ++n)
            acc[m][n] = (f32x4){0.f, 0.f, 0.f, 0.f};

    for (int k0 = 0; k0 < kslice; k0 += 32) {
        gload_lds16(gA0 + k0, lA0);
        gload_lds16(gA1 + k0, lA1);
        gload_lds16(gB + k0, lB);
        __syncthreads();   // drains vmcnt (gload_lds) before LDS reads
        bf16x8 a[2], b[4];
        a[0] = *(bf16x8*)&As[wid * 32 + l16][l4 * 8];
        a[1] = *(bf16x8*)&As[wid * 32 + 16 + l16][l4 * 8];
        #pragma unroll
        for (int n = 0; n < 4; ++n) b[n] = *(bf16x8*)&Bs[n * 16 + l16][l4 * 8];
        #pragma unroll
        for (int m = 0; m < 2; ++m)
            #pragma unroll
            for (int n = 0; n < 4; ++n)
                acc[m][n] = __builtin_amdgcn_mfma_f32_16x16x32_bf16(a[m], b[n], acc[m][n], 0, 0, 0);
        __syncthreads();   // all reads done before next-iter staging overwrites
    }

    if (KSPLIT > 1) {
        float* P = Yf + (size_t)blockIdx.z * M * N;
        #pragma unroll
        for (int m = 0; m < 2; ++m)
            #pragma unroll
            for (int n = 0; n < 4; ++n) {
                const int col = bn + n * 16 + l16;
                #pragma unroll
                for (int r = 0; r < 4; ++r) {
                    const int row = bm + wid * 32 + m * 16 + l4 * 4 + r;
                    P[(size_t)row * N + col] = acc[m][n][r];
                }
            }
    } else {
        #pragma unroll
        for (int m = 0; m < 2; ++m)
            #pragma unroll
            for (int n = 0; n < 4; ++n) {
                const int col = bn + n * 16 + l16;
                const float bz = bias[col];
                #pragma unroll
                for (int r = 0; r < 4; ++r) {
                    const int row = bm + wid * 32 + m * 16 + l4 * 4 + r;
                    float v = acc[m][n][r] + bz;
                    if (GELU_) v = gelu_tanh(v);
                    Yb[(size_t)row * N + col] = f2bf(v);
                }
            }
    }
}

// ---------------------------------------------------------------------------
// MFMA masked linear attention. One block per (64-row q-tile, head), 4 waves.
// ---------------------------------------------------------------------------
__global__ __launch_bounds__(256) void k_attn_mfma(const unsigned short* __restrict__ qkv,
                                                   const int* __restrict__ c,
                                                   const float* __restrict__ SB,  // [H,DH,DH]
                                                   unsigned short* __restrict__ out)
{
    __shared__ __align__(16) unsigned short Qs[64][72];
    __shared__ __align__(16) unsigned short Ks[64][72];
    __shared__ __align__(16) unsigned short VsT[64][72];  // VsT[e][s]
    __shared__ __align__(16) unsigned short Ss[64][72];   // S[q][s]; reused as SBsT[e][k] pre-loop
    __shared__ int cq[64], cs[64];
    const int h = blockIdx.y;
    const int q0 = blockIdx.x * 64;
    const int tid = threadIdx.x;
    const int lane = tid & 63;
    const int wid = tid >> 6;
    const int l16 = lane & 15, l4 = lane >> 4;
    const int wrow = wid * 16;
    const int r1 = tid >> 3, ccol = (tid & 7) * 8;

    *(bf16x8*)&Qs[r1][ccol]      = *(const bf16x8*)(qkv + (size_t)(q0 + r1) * TD3 + h * 64 + ccol);
    *(bf16x8*)&Qs[r1 + 32][ccol] = *(const bf16x8*)(qkv + (size_t)(q0 + r1 + 32) * TD3 + h * 64 + ccol);
    if (tid < 64) cq[tid] = c[q0 + tid];
    __syncthreads();
    const int cq0 = cq[0];

    f32x4 o[4];
    #pragma unroll
    for (int n = 0; n < 4; ++n) o[n] = (f32x4){0.f, 0.f, 0.f, 0.f};

    if (cq0 == 0) {
        for (int i = tid; i < 4096; i += 256) {
            int k = i >> 6, e = i & 63;
            Ss[e][k] = f2bf(SB[(h * 64 + k) * 64 + e]);
        }
        __syncthreads();
        bf16x8 aq0 = *(bf16x8*)&Qs[wrow + l16][l4 * 8];
        bf16x8 aq1 = *(bf16x8*)&Qs[wrow + l16][32 + l4 * 8];
        if (cq[wrow + l16] != 0) {
            aq0 = (bf16x8){0, 0, 0, 0, 0, 0, 0, 0};
            aq1 = (bf16x8){0, 0, 0, 0, 0, 0, 0, 0};
        }
        #pragma unroll
        for (int n = 0; n < 4; ++n) {
            o[n] = __builtin_amdgcn_mfma_f32_16x16x32_bf16(aq0, *(bf16x8*)&Ss[n * 16 + l16][l4 * 8], o[n], 0, 0, 0);
            o[n] = __builtin_amdgcn_mfma_f32_16x16x32_bf16(aq1, *(bf16x8*)&Ss[n * 16 + l16][32 + l4 * 8], o[n], 0, 0, 0);
        }
        __syncthreads();
    }

    for (int st = blockIdx.x; st >= 0; --st) {
        const int s0 = st * 64;
        if (st < (int)blockIdx.x && c[s0 + 63] < cq0) break;

        *(bf16x8*)&Ks[r1][ccol]      = *(const bf16x8*)(qkv + (size_t)(s0 + r1) * TD3 + 512 + h * 64 + ccol);
        *(bf16x8*)&Ks[r1 + 32][ccol] = *(const bf16x8*)(qkv + (size_t)(s0 + r1 + 32) * TD3 + 512 + h * 64 + ccol);
        {
            bf16x8 v1 = *(const bf16x8*)(qkv + (size_t)(s0 + r1) * TD3 + 1024 + h * 64 + ccol);
            bf16x8 v2 = *(const bf16x8*)(qkv + (size_t)(s0 + r1 + 32) * TD3 + 1024 + h * 64 + ccol);
            #pragma unroll
            for (int j = 0; j < 8; ++j) {
                VsT[ccol + j][r1]      = (unsigned short)v1[j];
                VsT[ccol + j][r1 + 32] = (unsigned short)v2[j];
            }
        }
        if (tid < 64) cs[tid] = c[s0 + tid];
        __syncthreads();

        f32x4 s_acc[4];
        #pragma unroll
        for (int n = 0; n < 4; ++n) s_acc[n] = (f32x4){0.f, 0.f, 0.f, 0.f};
        bf16x8 aq0 = *(bf16x8*)&Qs[wrow + l16][l4 * 8];
        bf16x8 aq1 = *(bf16x8*)&Qs[wrow + l16][32 + l4 * 8];
        #pragma unroll
        for (int n = 0; n < 4; ++n) {
            s_acc[n] = __builtin_amdgcn_mfma_f32_16x16x32_bf16(aq0, *(bf16x8*)&Ks[n * 16 + l16][l4 * 8], s_acc[n], 0, 0, 0);
            s_acc[n] = __builtin_amdgcn_mfma_f32_16x16x32_bf16(aq1, *(bf16x8*)&Ks[n * 16 + l16][32 + l4 * 8], s_acc[n], 0, 0, 0);
        }
        #pragma unroll
        for (int n = 0; n < 4; ++n) {
            const int sc_ = n * 16 + l16;
            const int sg = s0 + sc_;
            const int csv = cs[sc_];
            #pragma unroll
            for (int r = 0; r < 4; ++r) {
                const int qrow = wrow + l4 * 4 + r;
                float v = s_acc[n][r];
                if (!((q0 + qrow) >= sg && cq[qrow] == csv)) v = 0.f;
                Ss[qrow][sc_] = f2bf(v);
            }
        }
        bf16x8 as0 = *(bf16x8*)&Ss[wrow + l16][l4 * 8];
        bf16x8 as1 = *(bf16x8*)&Ss[wrow + l16][32 + l4 * 8];
        #pragma unroll
        for (int n = 0; n < 4; ++n) {
            o[n] = __builtin_amdgcn_mfma_f32_16x16x32_bf16(as0, *(bf16x8*)&VsT[n * 16 + l16][l4 * 8], o[n], 0, 0, 0);
            o[n] = __builtin_amdgcn_mfma_f32_16x16x32_bf16(as1, *(bf16x8*)&VsT[n * 16 + l16][32 + l4 * 8], o[n], 0, 0, 0);
        }
        __syncthreads();
    }

    #pragma unroll
    for (int n = 0; n < 4; ++n) {
        const int e = n * 16 + l16;
        #pragma unroll
        for (int r = 0; r < 4; ++r) {
            const int qrow = wrow + l4 * 4 + r;
            out[(size_t)(q0 + qrow) * DD + h * 64 + e] = f2bf(o[n][r]);
        }
    }
}

// ---------------------------------------------------------------------------
// State init: out = done_any ? 0 : state_blocks
// ---------------------------------------------------------------------------
__global__ __launch_bounds__(256) void k_state_init(const float* __restrict__ SB_all,
                                                    const int* __restrict__ c,
                                                    float* __restrict__ out)
{
    const int idx = blockIdx.x * 256 + threadIdx.x;
    const bool any = c[TT - 1] > 0;
    out[idx] = any ? 0.0f : SB_all[idx];
}

// ---------------------------------------------------------------------------
// State accumulate v2: suffix-only, one block per head, no atomics.
// c is non-decreasing; {t: c[t]==c_last} is the suffix [t_start, TT).
// Binary-search t_start, accumulate outer products, single-writer RMW.
// ---------------------------------------------------------------------------
__global__ __launch_bounds__(256) void k_state_acc2(const unsigned short* __restrict__ qkv,
                                                    const int* __restrict__ c,
                                                    float* __restrict__ st_out)  // [H,DH,DH]
{
    __shared__ int ts_sh;
    const int h = blockIdx.x;
    const int tid = threadIdx.x;
    if (tid == 0) {
        const int cl = c[TT - 1];
        int lo = 0, hi = TT - 1;
        while (lo < hi) { int mid = (lo + hi) >> 1; if (c[mid] < cl) lo = mid + 1; else hi = mid; }
        ts_sh = lo;
    }
    __syncthreads();
    const int t_start = ts_sh;

    const int d = tid >> 2;
    const int e0 = (tid & 3) * 16;
    float acc[16] = {};
    for (int t = t_start; t < TT; ++t) {
        float kd = bf2f(qkv[(size_t)t * TD3 + 512 + h * 64 + d]);
        const bf16x8* vr = (const bf16x8*)(qkv + (size_t)t * TD3 + 1024 + h * 64 + e0);
        bf16x8 va = vr[0], vb = vr[1];
        #pragma unroll
        for (int e = 0; e < 8; ++e) acc[e]     += kd * bf2f((unsigned short)va[e]);
        #pragma unroll
        for (int e = 0; e < 8; ++e) acc[e + 8] += kd * bf2f((unsigned short)vb[e]);
    }
    float* dst = st_out + (size_t)(h * 64 + d) * 64 + e0;
    #pragma unroll
    for (int e = 0; e < 16; ++e) dst[e] += acc[e];   // single writer per (h,d,e): no atomics
}

// ---------------------------------------------------------------------------
extern "C" void kernel_launch(void* const* d_in, const int* in_sizes, int n_in,
                              void* d_out, int out_size, void* d_ws, size_t ws_size,
                              hipStream_t stream)
{
    const float* obs        = (const float*)d_in[0];
    const float* rew_p      = (const float*)d_in[1];
    const int*   act_p      = (const int*)d_in[2];
    const unsigned char* done = (const unsigned char*)d_in[3];
    const int*   state_obs  = (const int*)d_in[4];
    const float* state_blocks = (const float*)d_in[5];
    const float* w_obs      = (const float*)d_in[6];
    const float* b_obs      = (const float*)d_in[7];
    const float* emb_act    = (const float*)d_in[8];
    const float* w_rew      = (const float*)d_in[9];
    const float* b_rew      = (const float*)d_in[10];
    const float* emb_time   = (const float*)d_in[11];
    const float* ln1_s      = (const float*)d_in[12];
    const float* ln1_b      = (const float*)d_in[13];
    const float* w_qkv      = (const float*)d_in[14];
    const float* b_qkv      = (const float*)d_in[15];
    const float* w_out      = (const float*)d_in[16];
    const float* b_out      = (const float*)d_in[17];
    const float* ln2_s      = (const float*)d_in[18];
    const float* ln2_b      = (const float*)d_in[19];
    const float* w_m1       = (const float*)d_in[20];
    const float* b_m1       = (const float*)d_in[21];
    const float* w_m2       = (const float*)d_in[22];
    const float* b_m2       = (const float*)d_in[23];
    const float* lnf_s      = (const float*)d_in[24];
    const float* lnf_b      = (const float*)d_in[25];
    const float* w_actor    = (const float*)d_in[26];
    const float* b_actor    = (const float*)d_in[27];
    const float* w_critic   = (const float*)d_in[28];
    const float* b_critic   = (const float*)d_in[29];

    float* out = (float*)d_out;

    // workspace layout
    char* ws = (char*)d_ws;
    int*   c_buf = (int*)ws;                             // [T]
    int*   t_buf = c_buf + TT;                           // [T]
    float* x     = (float*)(ws + 16384);                 // [T,D] fp32 (4MB)
    float* part  = x + (size_t)TT * DD;                  // [4,T,D] fp32 (16MB)
    unsigned short* qkvb = (unsigned short*)(part + (size_t)4 * TT * DD);  // [T,3D] bf16 (6MB)
    unsigned short* hbuf = qkvb + (size_t)TT * TD3;      // [T,D] bf16 (2MB)
    unsigned short* aout = hbuf + (size_t)TT * DD;       // [T,D] bf16 (2MB)
    unsigned short* mid  = aout + (size_t)TT * DD;       // [T,DFF] bf16 (8MB)
    unsigned short* wq_t = mid + (size_t)TT * DFF;       // [L,3D,D] bf16 (6MB)
    unsigned short* wo_t = wq_t + (size_t)LL * TD3 * DD; // [L,D,D] (2MB)
    unsigned short* wm1_t = wo_t + (size_t)LL * DD * DD; // [L,DFF,D] (8MB)
    unsigned short* wm2_t = wm1_t + (size_t)LL * DFF * DD; // [L,D,DFF] (8MB)

    // 1) scans (c, time) + time output
    k_scan<<<1, 256, 0, stream>>>(done, state_obs, c_buf, t_buf, out + OUT_TIME);

    // 2) fused embedding + layer-0 ln1
    k_embed_ln<<<TT, 64, 0, stream>>>(obs, rew_p, act_p, t_buf, w_obs, b_obs,
                                      emb_act, w_rew, b_rew, emb_time,
                                      ln1_s, ln1_b, x, hbuf);

    // 3) init states output
    k_state_init<<<LL * HH * DH * DH / 256, 256, 0, stream>>>(state_blocks, c_buf, out + OUT_STATES);

    // 4) all weight transposes in one launch
    k_w2bf_all<<<dim3(3072, LL), 256, 0, stream>>>(
        w_qkv, w_out, w_m1, w_m2, wq_t, wo_t, wm1_t, wm2_t);

    // 5) transformer layers (all GEMMs: 128x64 tiles, gload_lds staging)
    for (int i = 0; i < LL; ++i) {
        // qkv: [T,512]@[512,1536] -> bf16. grid 24x16 = 384 blocks.
        k_gemm5<1, false><<<dim3(TD3 / 64, TT / 128), 256, 0, stream>>>(
            hbuf, wq_t + (size_t)i * TD3 * DD, b_qkv + i * TD3, nullptr, qkvb, TT, TD3, DD);
        k_attn_mfma<<<dim3(TT / 64, HH), 256, 0, stream>>>(
            qkvb, c_buf, state_blocks + (size_t)i * HH * DH * DH, aout);
        k_state_acc2<<<HH, 256, 0, stream>>>(
            qkvb, c_buf, out + OUT_STATES + (size_t)i * HH * DH * DH);
        // out-proj: [T,512]@[512,512], split-K=2 -> partials. grid 8x16x2 = 256.
        k_gemm5<2, false><<<dim3(DD / 64, TT / 128, 2), 256, 0, stream>>>(
            aout, wo_t + (size_t)i * DD * DD, nullptr, part, nullptr, TT, DD, DD);
        // fused reduce(2) + residual + ln2 -> x, hbuf
        k_red_ln<2, false><<<TT / 4, 256, 0, stream>>>(x, part, b_out + i * DD,
            ln2_s + i * DD, ln2_b + i * DD, hbuf, nullptr, nullptr, nullptr, nullptr, nullptr);
        // m1: [T,512]@[512,2048] + gelu -> bf16 mid. grid 32x16 = 512 blocks.
        k_gemm5<1, true><<<dim3(DFF / 64, TT / 128), 256, 0, stream>>>(
            hbuf, wm1_t + (size_t)i * DFF * DD, b_m1 + i * DFF, nullptr, mid, TT, DFF, DD);
        // m2: [T,2048]@[2048,512], split-K=4 -> partials. grid 8x16x4 = 512.
        k_gemm5<4, false><<<dim3(DD / 64, TT / 128, 4), 256, 0, stream>>>(
            mid, wm2_t + (size_t)i * DD * DFF, nullptr, part, nullptr, TT, DD, DFF);
        // fused reduce(4) + residual + next-LN; last layer also computes heads
        if (i < LL - 1) {
            k_red_ln<4, false><<<TT / 4, 256, 0, stream>>>(x, part, b_m2 + i * DD,
                ln1_s + (i + 1) * DD, ln1_b + (i + 1) * DD, hbuf,
                nullptr, nullptr, nullptr, nullptr, nullptr);
        } else {
            k_red_ln<4, true><<<TT / 4, 256, 0, stream>>>(x, part, b_m2 + i * DD,
                lnf_s, lnf_b, hbuf, w_actor, b_actor, w_critic, b_critic, out);
        }
    }
}